// Round 2
// baseline (280.425 us; speedup 1.0000x reference)
//
#include <hip/hip_runtime.h>
#include <math.h>

#define D 64
#define K 512
#define ROWS 131072       // 32*64*64
#define NELEM (ROWS * D)  // 8388608
#define TGAP 64.0f        // flag threshold in 2^20-scaled units (= 6.1e-5 unscaled)
#define FLAGBIT (1 << 30)
#define RPB 128           // rows per block: 2 row-groups x 64 rows; 4 waves (2 rg x 2 col-halves)
#define NBLK (ROWS / RPB) // 1024 blocks -> 4 blocks/CU

typedef _Float16 half8 __attribute__((ext_vector_type(8)));
typedef float floatx4 __attribute__((ext_vector_type(4)));

// ws layout (bytes):
//   [0,8)            double loss accumulator
//   [8,12)           uint32 ticket counter (fused finalize)
//   [4096,6144)      float  Bn20[512]    column norms * 2^20 (numpy order, exact scale)
//   [8192,73728)     _Float16 gH[32768]  hi B-fragments, MFMA fragment order
//   [73728,139264)   _Float16 gL[32768]  lo B-fragments

// ---------------------------------------------------------------------------
// Setup: codebook -> scaled fp16 hi/lo in B-fragment order, + norms, + ws zero.
// Iterates the FRAGMENT index (coalesced 2B stores); inverts the permutation
// for the load (scattered 4B loads, L2-resident cb).
// forward: off = (((n>>4)*2 + (k>>5))*64 + ((k>>3)&3)*16 + (n&15))*8 + (k&7)
// ---------------------------------------------------------------------------
__global__ __launch_bounds__(512) void vq_setup(const float* __restrict__ cb,
                                                _Float16* __restrict__ gH,
                                                _Float16* __restrict__ gL,
                                                float* __restrict__ Bn,
                                                unsigned long long* __restrict__ zws) {
    int off = blockIdx.x * 512 + threadIdx.x;   // 64 blocks x 512 = 32768
    int j = off & 7;
    int frag = off >> 3;
    int n = ((frag >> 7) << 4) | (frag & 15);
    int k = (((frag >> 6) & 1) << 5) | (((frag >> 4) & 3) << 3) | j;
    float c = cb[k * K + n];
    float t = c * 4096.0f;                      // 2^12, exact
    _Float16 chh = (_Float16)t;
    float r = t - (float)chh;                   // exact
    gH[off] = chh;
    gL[off] = (_Float16)(r * 4096.0f);          // scale 2^24
    if (blockIdx.x == 1 && threadIdx.x < 4) zws[threadIdx.x] = 0ull;  // loss + ticket
    if (blockIdx.x == 0) {
#pragma clang fp contract(off)
        int jj = threadIdx.x;
        float b = 0.f;
        for (int kk = 0; kk < D; ++kk) { float cc = cb[kk * K + jj]; b = b + cc * cc; }
        Bn[jj] = b * 0x1p20f;                   // exact power-of-2 scale
    }
}

// ---------------------------------------------------------------------------
// Main: MFMA filter. 256 thr = 4 waves = 2 row-groups x 2 column-halves.
// Each wave: 64 rows (4 tiles of 16) x 256 columns (16 B-tile pairs) —
// same per-wave register set / arithmetic intensity as the 74us round-0
// kernel, but 2x the waves (16 waves/CU, 4/SIMD).
// A pre-scaled by -2 so MFMA accumulates (B - 2M)*2^20 directly (C-init = Bj).
// Cross-half best-2 merge through LDS; fused exact rescan + ticket finalize.
// ---------------------------------------------------------------------------
__global__ __launch_bounds__(256, 4) void vq_main(const float* __restrict__ x,
                                                  const float* __restrict__ cb,
                                                  const _Float16* __restrict__ gH,
                                                  const _Float16* __restrict__ gL,
                                                  const float* __restrict__ Bn,
                                                  float* __restrict__ out,
                                                  double* __restrict__ loss_acc,
                                                  unsigned int* __restrict__ ticket) {
    __shared__ float ldsB[K];
    __shared__ float m1buf[4][64];
    __shared__ float m2buf[4][64];
    __shared__ int   i1buf[4][64];
    __shared__ int   rowinfo[RPB];
    __shared__ unsigned int flagbits[4];
    __shared__ float wavesum[4];

    const int tid = threadIdx.x;
    const int lane = tid & 63;
    const int w = tid >> 6;
    const int ch = w & 1;     // column half: j in [ch*256, ch*256+256)
    const int rg = w >> 1;    // row group: 64 rows
    const int quad = lane >> 4;
    const int nn = lane & 15;

    ldsB[tid] = Bn[tid];
    ldsB[tid + 256] = Bn[tid + 256];
    if (tid < 4) flagbits[tid] = 0;

    const int blockBase = blockIdx.x * RPB;
    const int rowBase = blockBase + rg * 64;

    // A-fragments: lane holds A[m=nn][k=quad*8+j] per k-half s, scaled by -2:
    // hi at -2^9*x, residual *4096. The ch-pair wave re-reads the same rows;
    // those loads hit L1/L2 (same CU, same time) so HBM fetch stays ~1x.
    half8 xh[4][2], xl[4][2];
    #pragma unroll
    for (int tt = 0; tt < 4; ++tt) {
        #pragma unroll
        for (int s = 0; s < 2; ++s) {
            const float* xp = x + (size_t)(rowBase + tt * 16 + nn) * D + s * 32 + quad * 8;
            float4 v0 = *(const float4*)xp;
            float4 v1 = *(const float4*)(xp + 4);
            float vv[8] = {v0.x, v0.y, v0.z, v0.w, v1.x, v1.y, v1.z, v1.w};
            #pragma unroll
            for (int jj = 0; jj < 8; ++jj) {
                float t = vv[jj] * -512.0f;      // -2^9, exact
                _Float16 h = (_Float16)t;
                float r = t - (float)h;          // exact
                xh[tt][s][jj] = h;
                xl[tt][s][jj] = (_Float16)(r * 4096.0f);  // scale -2*2^20
            }
        }
    }
    __syncthreads();

    float m1[4][4], m2[4][4];
    int   i1[4][4];
    #pragma unroll
    for (int tt = 0; tt < 4; ++tt)
        #pragma unroll
        for (int r = 0; r < 4; ++r) { m1[tt][r] = INFINITY; m2[tt][r] = INFINITY; i1[tt][r] = 0; }

    const half8* bHp = (const half8*)gH;
    const half8* bLp = (const half8*)gL;

    #pragma unroll 2
    for (int t = 0; t < 16; ++t) {
        int tg = ch * 16 + t;
        half8 bh0 = bHp[(tg * 2 + 0) * 64 + lane];   // coalesced 16B/lane, L2-resident
        half8 bl0 = bLp[(tg * 2 + 0) * 64 + lane];
        half8 bh1 = bHp[(tg * 2 + 1) * 64 + lane];
        half8 bl1 = bLp[(tg * 2 + 1) * 64 + lane];
        int col = tg * 16 + nn;
        float Bj = ldsB[col];                        // B*2^20
        #pragma unroll
        for (int tt = 0; tt < 4; ++tt) {
            floatx4 a1 = {Bj, Bj, Bj, Bj};           // C-init: accumulate (B - 2M_hi)*2^20
            floatx4 a2 = {0.f, 0.f, 0.f, 0.f};      // cross terms at -2*2^32
            a2 = __builtin_amdgcn_mfma_f32_16x16x32_f16(xl[tt][0], bh0, a2, 0, 0, 0);
            a2 = __builtin_amdgcn_mfma_f32_16x16x32_f16(xh[tt][0], bl0, a2, 0, 0, 0);
            a1 = __builtin_amdgcn_mfma_f32_16x16x32_f16(xh[tt][0], bh0, a1, 0, 0, 0);
            a2 = __builtin_amdgcn_mfma_f32_16x16x32_f16(xl[tt][1], bh1, a2, 0, 0, 0);
            a2 = __builtin_amdgcn_mfma_f32_16x16x32_f16(xh[tt][1], bl1, a2, 0, 0, 0);
            a1 = __builtin_amdgcn_mfma_f32_16x16x32_f16(xh[tt][1], bh1, a1, 0, 0, 0);
            #pragma unroll
            for (int r = 0; r < 4; ++r) {
                float g = fmaf(0x1p-12f, a2[r], a1[r]);            // (B - 2M) * 2^20
                float old1 = m1[tt][r];
                // new m2 = 2nd-best of {old1, old2, g} = median of the three
                m2[tt][r] = __builtin_amdgcn_fmed3f(g, old1, m2[tt][r]);
                bool c1 = g < old1;
                m1[tt][r] = c1 ? g : old1;
                i1[tt][r] = c1 ? col : i1[tt][r];                  // strict <, j ascending
            }
        }
    }

    // merge best-2 across the 16 col-lanes (butterfly over low 4 lane bits)
    #pragma unroll
    for (int dlt = 1; dlt < 16; dlt <<= 1) {
        #pragma unroll
        for (int tt = 0; tt < 4; ++tt)
            #pragma unroll
            for (int r = 0; r < 4; ++r) {
                float om1 = __shfl_xor(m1[tt][r], dlt);
                int   oi1 = __shfl_xor(i1[tt][r], dlt);
                float om2 = __shfl_xor(m2[tt][r], dlt);
                bool ofirst = (om1 < m1[tt][r]) || (om1 == m1[tt][r] && oi1 < i1[tt][r]);
                float l1   = ofirst ? m1[tt][r] : om1;
                float cand = ofirst ? om2 : m2[tt][r];
                m1[tt][r] = ofirst ? om1 : m1[tt][r];
                i1[tt][r] = ofirst ? oi1 : i1[tt][r];
                m2[tt][r] = fminf(cand, l1);
            }
    }

    // publish per-wave (per column-half) best-2 to LDS
    if (nn == 0) {
        #pragma unroll
        for (int tt = 0; tt < 4; ++tt)
            #pragma unroll
            for (int r = 0; r < 4; ++r) {
                int rl = tt * 16 + quad * 4 + r;
                m1buf[w][rl] = m1[tt][r];
                m2buf[w][rl] = m2[tt][r];
                i1buf[w][rl] = i1[tt][r];
            }
    }
    __syncthreads();

    // cross-half merge: thread tid<128 owns block row tid
    if (tid < RPB) {
        int mrg = tid >> 6, mrl = tid & 63;
        float a1v = m1buf[mrg * 2 + 0][mrl];
        float a2v = m2buf[mrg * 2 + 0][mrl];
        int   ai  = i1buf[mrg * 2 + 0][mrl];    // j < 256
        float b1v = m1buf[mrg * 2 + 1][mrl];
        float b2v = m2buf[mrg * 2 + 1][mrl];
        int   bi  = i1buf[mrg * 2 + 1][mrl];    // j >= 256 (so ties -> a, lower index)
        bool bf = b1v < a1v;
        float f1 = bf ? b1v : a1v;
        int   fi = bf ? bi : ai;
        float f2 = fminf(fmaxf(a1v, b1v), bf ? b2v : a2v);
        bool flg = (f2 - f1) < TGAP;
        rowinfo[tid] = fi | (flg ? FLAGBIT : 0);
        if (flg) atomicOr(&flagbits[tid >> 5], 1u << (tid & 31));
    }
    __syncthreads();

    // coalesced output + loss for certain rows: wave w owns block rows [w*32, w*32+32)
    float lsum = 0.f;
    #pragma unroll
    for (int p = 0; p < 8; ++p) {
        int rl = w * 32 + p * 4 + quad;
        int info = rowinfo[rl];
        if (!(info & FLAGBIT)) {
            int j = info & 511;
            int kb = nn * 4;
            float q0 = cb[(kb + 0) * K + j];
            float q1 = cb[(kb + 1) * K + j];
            float q2 = cb[(kb + 2) * K + j];
            float q3 = cb[(kb + 3) * K + j];
            size_t row = (size_t)blockBase + rl;
            float4 xv = *(const float4*)(x + row * D + kb);
            float e0 = q0 - xv.x, e1 = q1 - xv.y, e2 = q2 - xv.z, e3 = q3 - xv.w;
            lsum += e0 * e0 + e1 * e1 + e2 * e2 + e3 * e3;
            *(float4*)(out + row * D + kb) = make_float4(q0, q1, q2, q3);
        }
    }

    // fused exact rescan: wave w handles its own 32-row flag word.
    // Exact numpy-order pipeline; lane handles 8 columns (j = lane + 64m).
    unsigned int fmask = flagbits[w];
    if (fmask) {
#pragma clang fp contract(off)
        float bn[8];
        #pragma unroll
        for (int m = 0; m < 8; ++m) bn[m] = 0.f;
        for (int k = 0; k < D; ++k) {
            const float* crow = cb + k * K + lane;
            #pragma unroll
            for (int m = 0; m < 8; ++m) {
                float c = crow[m * 64];
                bn[m] = bn[m] + c * c;
            }
        }
        while (fmask) {
            int b = __builtin_ctz(fmask);
            fmask &= fmask - 1;
            int row = blockBase + w * 32 + b;
            const float* xr = x + (size_t)row * D;
            // A = np.sum(x**2, axis=1): pairwise n=64 emulation
            float A0;
            {
                float rr[8];
                #pragma unroll
                for (int l = 0; l < 8; ++l) rr[l] = xr[l] * xr[l];
                #pragma unroll
                for (int m = 1; m < 8; ++m)
                    #pragma unroll
                    for (int l = 0; l < 8; ++l) {
                        float q = xr[8 * m + l] * xr[8 * m + l];
                        rr[l] = rr[l] + q;
                    }
                A0 = ((rr[0] + rr[1]) + (rr[2] + rr[3])) + ((rr[4] + rr[5]) + (rr[6] + rr[7]));
            }
            float a[8];
            #pragma unroll
            for (int m = 0; m < 8; ++m) a[m] = 0.f;
            for (int k = 0; k < D; ++k) {
                float xk = xr[k];
                const float* crow = cb + k * K + lane;
                #pragma unroll
                for (int m = 0; m < 8; ++m)
                    a[m] = fmaf(xk, crow[m * 64], a[m]);   // sequential-k fma chain
            }
            float db = INFINITY; int jb = 0x7fffffff;
            #pragma unroll
            for (int m = 0; m < 8; ++m) {
                float s = A0 + bn[m];
                float t2 = 2.0f * a[m];
                float d = s - t2;                  // fl(fl(A+B) - fl(2M))
                int j = lane + (m << 6);
                if (d < db) { db = d; jb = j; }
            }
            for (int s = 1; s < 64; s <<= 1) {     // first-index global argmin
                float od = __shfl_xor(db, s);
                int oj = __shfl_xor(jb, s);
                if ((od < db) || (od == db && oj < jb)) { db = od; jb = oj; }
            }
            float q = cb[lane * K + jb];
            out[(size_t)row * D + lane] = q;
            float e = q - xr[lane];
            lsum += e * e;
        }
    }

    #pragma unroll
    for (int off = 32; off > 0; off >>= 1) lsum += __shfl_down(lsum, off);
    if (lane == 0) wavesum[w] = lsum;
    __syncthreads();
    if (tid == 0) {
        double tot = (double)wavesum[0] + (double)wavesum[1]
                   + (double)wavesum[2] + (double)wavesum[3];
        atomicAdd(loss_acc, tot);
        __threadfence();
        unsigned int my = atomicAdd(ticket, 1u);
        if (my == (unsigned int)(gridDim.x - 1)) {
            // last block: all prior loss adds are ordered before their tickets
            double total = atomicAdd(loss_acc, 0.0);
            out[NELEM] = (float)(total * (1.25 / (double)NELEM));  // (1+beta)*mean
        }
    }
}

extern "C" void kernel_launch(void* const* d_in, const int* in_sizes, int n_in,
                              void* d_out, int out_size, void* d_ws, size_t ws_size,
                              hipStream_t stream) {
    const float* x  = (const float*)d_in[0];   // [32,64,64,64] fp32
    const float* cb = (const float*)d_in[1];   // [64,512] fp32
    float* out = (float*)d_out;                // [8388608] out + [1] loss
    double* loss_acc     = (double*)d_ws;
    unsigned int* ticket = (unsigned int*)((char*)d_ws + 8);
    float* Bn        = (float*)((char*)d_ws + 4096);
    _Float16* gH     = (_Float16*)((char*)d_ws + 8192);
    _Float16* gL     = (_Float16*)((char*)d_ws + 73728);

    vq_setup<<<64, 512, 0, stream>>>(cb, gH, gL, Bn, (unsigned long long*)d_ws);
    vq_main<<<NBLK, 256, 0, stream>>>(x, cb, gH, gL, Bn, out, loss_acc, ticket);
}

// Round 3
// 217.977 us; speedup vs baseline: 1.2865x; 1.2865x over previous
//
#include <hip/hip_runtime.h>
#include <math.h>

#define D 64
#define K 512
#define ROWS 131072       // 32*64*64
#define NELEM (ROWS * D)  // 8388608
#define TGAP 64.0f        // flag threshold in 2^20-scaled units (= 6.1e-5 unscaled)
#define FLAGBIT (1 << 30)
#define RPB 128           // rows per block: 2 row-groups x 64 rows; 4 waves (2 rg x 2 col-halves)
#define NBLK (ROWS / RPB) // 1024 blocks

typedef _Float16 half8 __attribute__((ext_vector_type(8)));
typedef float floatx4 __attribute__((ext_vector_type(4)));

// ws layout (bytes):
//   [0,8)            double loss accumulator
//   [8,12)           uint32 ticket counter (fused finalize)
//   [4096,6144)      float  Bn20[512]    column norms * 2^20 (numpy order, exact scale)
//   [8192,73728)     _Float16 gH[32768]  hi B-fragments, MFMA fragment order
//   [73728,139264)   _Float16 gL[32768]  lo B-fragments

// ---------------------------------------------------------------------------
// Setup: codebook -> scaled fp16 hi/lo in B-fragment order, + norms, + ws zero.
// Iterates the FRAGMENT index (coalesced 2B stores); inverts the permutation
// for the load (scattered 4B loads, L2-resident cb).
// forward: off = (((n>>4)*2 + (k>>5))*64 + ((k>>3)&3)*16 + (n&15))*8 + (k&7)
// ---------------------------------------------------------------------------
__global__ __launch_bounds__(512) void vq_setup(const float* __restrict__ cb,
                                                _Float16* __restrict__ gH,
                                                _Float16* __restrict__ gL,
                                                float* __restrict__ Bn,
                                                unsigned long long* __restrict__ zws) {
    int off = blockIdx.x * 512 + threadIdx.x;   // 64 blocks x 512 = 32768
    int j = off & 7;
    int frag = off >> 3;
    int n = ((frag >> 7) << 4) | (frag & 15);
    int k = (((frag >> 6) & 1) << 5) | (((frag >> 4) & 3) << 3) | j;
    float c = cb[k * K + n];
    float t = c * 4096.0f;                      // 2^12, exact
    _Float16 chh = (_Float16)t;
    float r = t - (float)chh;                   // exact
    gH[off] = chh;
    gL[off] = (_Float16)(r * 4096.0f);          // scale 2^24
    if (blockIdx.x == 1 && threadIdx.x < 4) zws[threadIdx.x] = 0ull;  // loss + ticket
    if (blockIdx.x == 0) {
#pragma clang fp contract(off)
        int jj = threadIdx.x;
        float b = 0.f;
        for (int kk = 0; kk < D; ++kk) { float cc = cb[kk * K + jj]; b = b + cc * cc; }
        Bn[jj] = b * 0x1p20f;                   // exact power-of-2 scale
    }
}

// ---------------------------------------------------------------------------
// Main: MFMA filter. 256 thr = 4 waves = 2 row-groups x 2 column-halves.
// Each wave: 64 rows (4 tiles of 16) x 256 columns (16 B-tile pairs) —
// round-0 per-wave register set / arithmetic intensity, 2x the wave count.
// __launch_bounds__(256, 2): min-waves=2 keeps the allocator at the ~124-VGPR
// tier (4 waves/SIMD capable) WITHOUT spilling. (256,4) made it squeeze to
// 64 VGPR and spill ~270 MB to scratch in rounds 1-2.
// A pre-scaled by -2 so MFMA accumulates (B - 2M)*2^20 directly (C-init = Bj).
// Cross-half best-2 merge through LDS; fused exact rescan + ticket finalize.
// ---------------------------------------------------------------------------
__global__ __launch_bounds__(256, 2) void vq_main(const float* __restrict__ x,
                                                  const float* __restrict__ cb,
                                                  const _Float16* __restrict__ gH,
                                                  const _Float16* __restrict__ gL,
                                                  const float* __restrict__ Bn,
                                                  float* __restrict__ out,
                                                  double* __restrict__ loss_acc,
                                                  unsigned int* __restrict__ ticket) {
    __shared__ float ldsB[K];
    __shared__ float m1buf[4][64];
    __shared__ float m2buf[4][64];
    __shared__ int   i1buf[4][64];
    __shared__ int   rowinfo[RPB];
    __shared__ unsigned int flagbits[4];
    __shared__ float wavesum[4];

    const int tid = threadIdx.x;
    const int lane = tid & 63;
    const int w = tid >> 6;
    const int ch = w & 1;     // column half: j in [ch*256, ch*256+256)
    const int rg = w >> 1;    // row group: 64 rows
    const int quad = lane >> 4;
    const int nn = lane & 15;

    ldsB[tid] = Bn[tid];
    ldsB[tid + 256] = Bn[tid + 256];
    if (tid < 4) flagbits[tid] = 0;

    const int blockBase = blockIdx.x * RPB;
    const int rowBase = blockBase + rg * 64;

    // A-fragments: lane holds A[m=nn][k=quad*8+j] per k-half s, scaled by -2:
    // hi at -2^9*x, residual *4096. The ch-pair wave re-reads the same rows;
    // those loads hit L1/L2 (same CU, same time) so HBM fetch stays ~1x.
    half8 xh[4][2], xl[4][2];
    #pragma unroll
    for (int tt = 0; tt < 4; ++tt) {
        #pragma unroll
        for (int s = 0; s < 2; ++s) {
            const float* xp = x + (size_t)(rowBase + tt * 16 + nn) * D + s * 32 + quad * 8;
            float4 v0 = *(const float4*)xp;
            float4 v1 = *(const float4*)(xp + 4);
            float vv[8] = {v0.x, v0.y, v0.z, v0.w, v1.x, v1.y, v1.z, v1.w};
            #pragma unroll
            for (int jj = 0; jj < 8; ++jj) {
                float t = vv[jj] * -512.0f;      // -2^9, exact
                _Float16 h = (_Float16)t;
                float r = t - (float)h;          // exact
                xh[tt][s][jj] = h;
                xl[tt][s][jj] = (_Float16)(r * 4096.0f);  // scale -2*2^20
            }
        }
    }
    __syncthreads();

    float m1[4][4], m2[4][4];
    int   i1[4][4];
    #pragma unroll
    for (int tt = 0; tt < 4; ++tt)
        #pragma unroll
        for (int r = 0; r < 4; ++r) { m1[tt][r] = INFINITY; m2[tt][r] = INFINITY; i1[tt][r] = 0; }

    const half8* bHp = (const half8*)gH;
    const half8* bLp = (const half8*)gL;

    #pragma unroll 2
    for (int t = 0; t < 16; ++t) {
        int tg = ch * 16 + t;
        half8 bh0 = bHp[(tg * 2 + 0) * 64 + lane];   // coalesced 16B/lane, L2-resident
        half8 bl0 = bLp[(tg * 2 + 0) * 64 + lane];
        half8 bh1 = bHp[(tg * 2 + 1) * 64 + lane];
        half8 bl1 = bLp[(tg * 2 + 1) * 64 + lane];
        int col = tg * 16 + nn;
        float Bj = ldsB[col];                        // B*2^20
        #pragma unroll
        for (int tt = 0; tt < 4; ++tt) {
            floatx4 a1 = {Bj, Bj, Bj, Bj};           // C-init: accumulate (B - 2M_hi)*2^20
            floatx4 a2 = {0.f, 0.f, 0.f, 0.f};      // cross terms at -2*2^32
            a2 = __builtin_amdgcn_mfma_f32_16x16x32_f16(xl[tt][0], bh0, a2, 0, 0, 0);
            a2 = __builtin_amdgcn_mfma_f32_16x16x32_f16(xh[tt][0], bl0, a2, 0, 0, 0);
            a1 = __builtin_amdgcn_mfma_f32_16x16x32_f16(xh[tt][0], bh0, a1, 0, 0, 0);
            a2 = __builtin_amdgcn_mfma_f32_16x16x32_f16(xl[tt][1], bh1, a2, 0, 0, 0);
            a2 = __builtin_amdgcn_mfma_f32_16x16x32_f16(xh[tt][1], bl1, a2, 0, 0, 0);
            a1 = __builtin_amdgcn_mfma_f32_16x16x32_f16(xh[tt][1], bh1, a1, 0, 0, 0);
            #pragma unroll
            for (int r = 0; r < 4; ++r) {
                float g = fmaf(0x1p-12f, a2[r], a1[r]);            // (B - 2M) * 2^20
                float old1 = m1[tt][r];
                // new m2 = 2nd-best of {old1, old2, g} = median of the three
                m2[tt][r] = __builtin_amdgcn_fmed3f(g, old1, m2[tt][r]);
                bool c1 = g < old1;
                m1[tt][r] = c1 ? g : old1;
                i1[tt][r] = c1 ? col : i1[tt][r];                  // strict <, j ascending
            }
        }
    }

    // merge best-2 across the 16 col-lanes (butterfly over low 4 lane bits)
    #pragma unroll
    for (int dlt = 1; dlt < 16; dlt <<= 1) {
        #pragma unroll
        for (int tt = 0; tt < 4; ++tt)
            #pragma unroll
            for (int r = 0; r < 4; ++r) {
                float om1 = __shfl_xor(m1[tt][r], dlt);
                int   oi1 = __shfl_xor(i1[tt][r], dlt);
                float om2 = __shfl_xor(m2[tt][r], dlt);
                bool ofirst = (om1 < m1[tt][r]) || (om1 == m1[tt][r] && oi1 < i1[tt][r]);
                float l1   = ofirst ? m1[tt][r] : om1;
                float cand = ofirst ? om2 : m2[tt][r];
                m1[tt][r] = ofirst ? om1 : m1[tt][r];
                i1[tt][r] = ofirst ? oi1 : i1[tt][r];
                m2[tt][r] = fminf(cand, l1);
            }
    }

    // publish per-wave (per column-half) best-2 to LDS
    if (nn == 0) {
        #pragma unroll
        for (int tt = 0; tt < 4; ++tt)
            #pragma unroll
            for (int r = 0; r < 4; ++r) {
                int rl = tt * 16 + quad * 4 + r;
                m1buf[w][rl] = m1[tt][r];
                m2buf[w][rl] = m2[tt][r];
                i1buf[w][rl] = i1[tt][r];
            }
    }
    __syncthreads();

    // cross-half merge: thread tid<128 owns block row tid
    if (tid < RPB) {
        int mrg = tid >> 6, mrl = tid & 63;
        float a1v = m1buf[mrg * 2 + 0][mrl];
        float a2v = m2buf[mrg * 2 + 0][mrl];
        int   ai  = i1buf[mrg * 2 + 0][mrl];    // j < 256
        float b1v = m1buf[mrg * 2 + 1][mrl];
        float b2v = m2buf[mrg * 2 + 1][mrl];
        int   bi  = i1buf[mrg * 2 + 1][mrl];    // j >= 256 (so ties -> a, lower index)
        bool bf = b1v < a1v;
        float f1 = bf ? b1v : a1v;
        int   fi = bf ? bi : ai;
        float f2 = fminf(fmaxf(a1v, b1v), bf ? b2v : a2v);
        bool flg = (f2 - f1) < TGAP;
        rowinfo[tid] = fi | (flg ? FLAGBIT : 0);
        if (flg) atomicOr(&flagbits[tid >> 5], 1u << (tid & 31));
    }
    __syncthreads();

    // coalesced output + loss for certain rows: wave w owns block rows [w*32, w*32+32)
    float lsum = 0.f;
    #pragma unroll
    for (int p = 0; p < 8; ++p) {
        int rl = w * 32 + p * 4 + quad;
        int info = rowinfo[rl];
        if (!(info & FLAGBIT)) {
            int j = info & 511;
            int kb = nn * 4;
            float q0 = cb[(kb + 0) * K + j];
            float q1 = cb[(kb + 1) * K + j];
            float q2 = cb[(kb + 2) * K + j];
            float q3 = cb[(kb + 3) * K + j];
            size_t row = (size_t)blockBase + rl;
            float4 xv = *(const float4*)(x + row * D + kb);
            float e0 = q0 - xv.x, e1 = q1 - xv.y, e2 = q2 - xv.z, e3 = q3 - xv.w;
            lsum += e0 * e0 + e1 * e1 + e2 * e2 + e3 * e3;
            *(float4*)(out + row * D + kb) = make_float4(q0, q1, q2, q3);
        }
    }

    // fused exact rescan: wave w handles its own 32-row flag word.
    // Exact numpy-order pipeline; lane handles 8 columns (j = lane + 64m).
    unsigned int fmask = flagbits[w];
    if (fmask) {
#pragma clang fp contract(off)
        float bn[8];
        #pragma unroll
        for (int m = 0; m < 8; ++m) bn[m] = 0.f;
        for (int k = 0; k < D; ++k) {
            const float* crow = cb + k * K + lane;
            #pragma unroll
            for (int m = 0; m < 8; ++m) {
                float c = crow[m * 64];
                bn[m] = bn[m] + c * c;
            }
        }
        while (fmask) {
            int b = __builtin_ctz(fmask);
            fmask &= fmask - 1;
            int row = blockBase + w * 32 + b;
            const float* xr = x + (size_t)row * D;
            // A = np.sum(x**2, axis=1): pairwise n=64 emulation
            float A0;
            {
                float rr[8];
                #pragma unroll
                for (int l = 0; l < 8; ++l) rr[l] = xr[l] * xr[l];
                #pragma unroll
                for (int m = 1; m < 8; ++m)
                    #pragma unroll
                    for (int l = 0; l < 8; ++l) {
                        float q = xr[8 * m + l] * xr[8 * m + l];
                        rr[l] = rr[l] + q;
                    }
                A0 = ((rr[0] + rr[1]) + (rr[2] + rr[3])) + ((rr[4] + rr[5]) + (rr[6] + rr[7]));
            }
            float a[8];
            #pragma unroll
            for (int m = 0; m < 8; ++m) a[m] = 0.f;
            for (int k = 0; k < D; ++k) {
                float xk = xr[k];
                const float* crow = cb + k * K + lane;
                #pragma unroll
                for (int m = 0; m < 8; ++m)
                    a[m] = fmaf(xk, crow[m * 64], a[m]);   // sequential-k fma chain
            }
            float db = INFINITY; int jb = 0x7fffffff;
            #pragma unroll
            for (int m = 0; m < 8; ++m) {
                float s = A0 + bn[m];
                float t2 = 2.0f * a[m];
                float d = s - t2;                  // fl(fl(A+B) - fl(2M))
                int j = lane + (m << 6);
                if (d < db) { db = d; jb = j; }
            }
            for (int s = 1; s < 64; s <<= 1) {     // first-index global argmin
                float od = __shfl_xor(db, s);
                int oj = __shfl_xor(jb, s);
                if ((od < db) || (od == db && oj < jb)) { db = od; jb = oj; }
            }
            float q = cb[lane * K + jb];
            out[(size_t)row * D + lane] = q;
            float e = q - xr[lane];
            lsum += e * e;
        }
    }

    #pragma unroll
    for (int off = 32; off > 0; off >>= 1) lsum += __shfl_down(lsum, off);
    if (lane == 0) wavesum[w] = lsum;
    __syncthreads();
    if (tid == 0) {
        double tot = (double)wavesum[0] + (double)wavesum[1]
                   + (double)wavesum[2] + (double)wavesum[3];
        atomicAdd(loss_acc, tot);
        __threadfence();
        unsigned int my = atomicAdd(ticket, 1u);
        if (my == (unsigned int)(gridDim.x - 1)) {
            // last block: all prior loss adds are ordered before their tickets
            double total = atomicAdd(loss_acc, 0.0);
            out[NELEM] = (float)(total * (1.25 / (double)NELEM));  // (1+beta)*mean
        }
    }
}

extern "C" void kernel_launch(void* const* d_in, const int* in_sizes, int n_in,
                              void* d_out, int out_size, void* d_ws, size_t ws_size,
                              hipStream_t stream) {
    const float* x  = (const float*)d_in[0];   // [32,64,64,64] fp32
    const float* cb = (const float*)d_in[1];   // [64,512] fp32
    float* out = (float*)d_out;                // [8388608] out + [1] loss
    double* loss_acc     = (double*)d_ws;
    unsigned int* ticket = (unsigned int*)((char*)d_ws + 8);
    float* Bn        = (float*)((char*)d_ws + 4096);
    _Float16* gH     = (_Float16*)((char*)d_ws + 8192);
    _Float16* gL     = (_Float16*)((char*)d_ws + 73728);

    vq_setup<<<64, 512, 0, stream>>>(cb, gH, gL, Bn, (unsigned long long*)d_ws);
    vq_main<<<NBLK, 256, 0, stream>>>(x, cb, gH, gL, Bn, out, loss_acc, ticket);
}

// Round 4
// 206.748 us; speedup vs baseline: 1.3564x; 1.0543x over previous
//
#include <hip/hip_runtime.h>
#include <math.h>

#define D 64
#define K 512
#define ROWS 131072       // 32*64*64
#define NELEM (ROWS * D)  // 8388608
#define TGAP 64.0f        // flag threshold in 2^20-scaled units (= 6.1e-5 unscaled)
#define FLAGBIT (1 << 30)
#define RPB 128           // rows per block: 4 waves x 32 rows
#define NBLK (ROWS / RPB) // 1024 blocks -> 4 blocks/CU, 16 waves/CU

typedef _Float16 half8 __attribute__((ext_vector_type(8)));
typedef float floatx4 __attribute__((ext_vector_type(4)));

// ws layout (bytes):
//   [0,8)            double loss accumulator
//   [8,12)           uint32 ticket counter (fused finalize)
//   [4096,6144)      float  Bn20[512]    column norms * 2^20 (numpy order, exact scale)
//   [8192,73728)     _Float16 gH[32768]  hi B-fragments, MFMA fragment order
//   [73728,139264)   _Float16 gL[32768]  lo B-fragments

// ---------------------------------------------------------------------------
// Setup: codebook -> scaled fp16 hi/lo in B-fragment order, + norms, + ws zero.
// Iterates the FRAGMENT index (coalesced 2B stores); inverts the permutation
// for the load (scattered 4B loads, L2-resident cb).
// forward: off = (((n>>4)*2 + (k>>5))*64 + ((k>>3)&3)*16 + (n&15))*8 + (k&7)
// ---------------------------------------------------------------------------
__global__ __launch_bounds__(512) void vq_setup(const float* __restrict__ cb,
                                                _Float16* __restrict__ gH,
                                                _Float16* __restrict__ gL,
                                                float* __restrict__ Bn,
                                                unsigned long long* __restrict__ zws) {
    int off = blockIdx.x * 512 + threadIdx.x;   // 64 blocks x 512 = 32768
    int j = off & 7;
    int frag = off >> 3;
    int n = ((frag >> 7) << 4) | (frag & 15);
    int k = (((frag >> 6) & 1) << 5) | (((frag >> 4) & 3) << 3) | j;
    float c = cb[k * K + n];
    float t = c * 4096.0f;                      // 2^12, exact
    _Float16 chh = (_Float16)t;
    float r = t - (float)chh;                   // exact
    gH[off] = chh;
    gL[off] = (_Float16)(r * 4096.0f);          // scale 2^24
    if (blockIdx.x == 1 && threadIdx.x < 4) zws[threadIdx.x] = 0ull;  // loss + ticket
    if (blockIdx.x == 0) {
#pragma clang fp contract(off)
        int jj = threadIdx.x;
        float b = 0.f;
        for (int kk = 0; kk < D; ++kk) { float cc = cb[kk * K + jj]; b = b + cc * cc; }
        Bn[jj] = b * 0x1p20f;                   // exact power-of-2 scale
    }
}

// ---------------------------------------------------------------------------
// Main: MFMA filter. 256 thr = 4 waves, 32 rows/wave (2 tiles of 16),
// each wave scans all 512 columns (no cross-wave merge needed).
// amdgpu_waves_per_eu(4,4): pins the register allocator to the 4-waves/SIMD
// tier (128-VGPR budget) and FORBIDS tier-boosting. Rounds 0-3 showed the
// allocator always lands on a tier boundary (124/84/64) and squeezes below
// the live set when allowed, rematerializing inside the hot loop.
// Live set here ~85 regs: A-frags 32 + best2 state 24 + B-frags 16 + misc.
// A pre-scaled by -2 so MFMA accumulates (B - 2M)*2^20 directly (C-init = Bj).
// Fused exact rescan of flagged rows (per-wave 32-bit mask) + ticket finalize.
// ---------------------------------------------------------------------------
__global__ __launch_bounds__(256) __attribute__((amdgpu_waves_per_eu(4, 4)))
void vq_main(const float* __restrict__ x,
             const float* __restrict__ cb,
             const _Float16* __restrict__ gH,
             const _Float16* __restrict__ gL,
             const float* __restrict__ Bn,
             float* __restrict__ out,
             double* __restrict__ loss_acc,
             unsigned int* __restrict__ ticket) {
    __shared__ float ldsB[K];
    __shared__ int rowinfo[4][32];
    __shared__ unsigned int flagbits[4];
    __shared__ float wavesum[4];

    const int tid = threadIdx.x;
    const int lane = tid & 63;
    const int w = tid >> 6;
    const int quad = lane >> 4;
    const int nn = lane & 15;

    ldsB[tid] = Bn[tid];
    ldsB[tid + 256] = Bn[tid + 256];
    if (tid < 4) flagbits[tid] = 0;

    const int rowBase = blockIdx.x * RPB + w * 32;

    // A-fragments: lane holds A[m=nn][k=quad*8+j] per k-half s, scaled by -2:
    // hi at -2^9*x, residual *4096 -> lo pairs with bl at combined 2^-12 shift.
    half8 xh[2][2], xl[2][2];
    #pragma unroll
    for (int tt = 0; tt < 2; ++tt) {
        #pragma unroll
        for (int s = 0; s < 2; ++s) {
            const float* xp = x + (size_t)(rowBase + tt * 16 + nn) * D + s * 32 + quad * 8;
            float4 v0 = *(const float4*)xp;
            float4 v1 = *(const float4*)(xp + 4);
            float vv[8] = {v0.x, v0.y, v0.z, v0.w, v1.x, v1.y, v1.z, v1.w};
            #pragma unroll
            for (int jj = 0; jj < 8; ++jj) {
                float t = vv[jj] * -512.0f;      // -2^9, exact
                _Float16 h = (_Float16)t;
                float r = t - (float)h;          // exact
                xh[tt][s][jj] = h;
                xl[tt][s][jj] = (_Float16)(r * 4096.0f);  // scale -2*2^20
            }
        }
    }
    __syncthreads();

    float m1[2][4], m2[2][4];
    int   i1[2][4];
    #pragma unroll
    for (int tt = 0; tt < 2; ++tt)
        #pragma unroll
        for (int r = 0; r < 4; ++r) { m1[tt][r] = INFINITY; m2[tt][r] = INFINITY; i1[tt][r] = 0; }

    const half8* bHp = (const half8*)gH;
    const half8* bLp = (const half8*)gL;

    #pragma unroll 2
    for (int t = 0; t < 32; ++t) {
        half8 bh0 = bHp[(t * 2 + 0) * 64 + lane];   // coalesced 16B/lane, L2-resident
        half8 bl0 = bLp[(t * 2 + 0) * 64 + lane];
        half8 bh1 = bHp[(t * 2 + 1) * 64 + lane];
        half8 bl1 = bLp[(t * 2 + 1) * 64 + lane];
        int col = t * 16 + nn;
        float Bj = ldsB[col];                        // B*2^20
        #pragma unroll
        for (int tt = 0; tt < 2; ++tt) {
            floatx4 a1 = {Bj, Bj, Bj, Bj};           // C-init: accumulate (B - 2M_hi)*2^20
            floatx4 a2 = {0.f, 0.f, 0.f, 0.f};      // cross terms at -2*2^32
            a2 = __builtin_amdgcn_mfma_f32_16x16x32_f16(xl[tt][0], bh0, a2, 0, 0, 0);
            a2 = __builtin_amdgcn_mfma_f32_16x16x32_f16(xh[tt][0], bl0, a2, 0, 0, 0);
            a1 = __builtin_amdgcn_mfma_f32_16x16x32_f16(xh[tt][0], bh0, a1, 0, 0, 0);
            a2 = __builtin_amdgcn_mfma_f32_16x16x32_f16(xl[tt][1], bh1, a2, 0, 0, 0);
            a2 = __builtin_amdgcn_mfma_f32_16x16x32_f16(xh[tt][1], bl1, a2, 0, 0, 0);
            a1 = __builtin_amdgcn_mfma_f32_16x16x32_f16(xh[tt][1], bh1, a1, 0, 0, 0);
            #pragma unroll
            for (int r = 0; r < 4; ++r) {
                float g = fmaf(0x1p-12f, a2[r], a1[r]);            // (B - 2M) * 2^20
                float old1 = m1[tt][r];
                // new m2 = 2nd-best of {old1, old2, g} = median of the three
                m2[tt][r] = __builtin_amdgcn_fmed3f(g, old1, m2[tt][r]);
                bool c1 = g < old1;
                m1[tt][r] = c1 ? g : old1;
                i1[tt][r] = c1 ? col : i1[tt][r];                  // strict <, j ascending
            }
        }
    }

    // merge best-2 across the 16 col-lanes (butterfly over low 4 lane bits)
    #pragma unroll
    for (int dlt = 1; dlt < 16; dlt <<= 1) {
        #pragma unroll
        for (int tt = 0; tt < 2; ++tt)
            #pragma unroll
            for (int r = 0; r < 4; ++r) {
                float om1 = __shfl_xor(m1[tt][r], dlt);
                int   oi1 = __shfl_xor(i1[tt][r], dlt);
                float om2 = __shfl_xor(m2[tt][r], dlt);
                bool ofirst = (om1 < m1[tt][r]) || (om1 == m1[tt][r] && oi1 < i1[tt][r]);
                float l1   = ofirst ? m1[tt][r] : om1;
                float cand = ofirst ? om2 : m2[tt][r];
                m1[tt][r] = ofirst ? om1 : m1[tt][r];
                i1[tt][r] = ofirst ? oi1 : i1[tt][r];
                m2[tt][r] = fminf(cand, l1);
            }
    }

    // record results; flagged rows -> per-wave LDS bitmap word
    if (nn == 0) {
        #pragma unroll
        for (int tt = 0; tt < 2; ++tt)
            #pragma unroll
            for (int r = 0; r < 4; ++r) {
                int rl = tt * 16 + quad * 4 + r;
                bool flg = (m2[tt][r] - m1[tt][r]) < TGAP;
                rowinfo[w][rl] = i1[tt][r] | (flg ? FLAGBIT : 0);
                if (flg) atomicOr(&flagbits[w], 1u << rl);
            }
    }
    __syncthreads();

    // coalesced output + loss for certain rows
    float lsum = 0.f;
    #pragma unroll
    for (int tt = 0; tt < 2; ++tt) {
        #pragma unroll
        for (int p = 0; p < 4; ++p) {
            int rl = tt * 16 + p * 4 + quad;
            int info = rowinfo[w][rl];
            if (!(info & FLAGBIT)) {
                int j = info & 511;
                int kb = nn * 4;
                float q0 = cb[(kb + 0) * K + j];
                float q1 = cb[(kb + 1) * K + j];
                float q2 = cb[(kb + 2) * K + j];
                float q3 = cb[(kb + 3) * K + j];
                size_t row = (size_t)rowBase + rl;
                float4 xv = *(const float4*)(x + row * D + kb);
                float e0 = q0 - xv.x, e1 = q1 - xv.y, e2 = q2 - xv.z, e3 = q3 - xv.w;
                lsum += e0 * e0 + e1 * e1 + e2 * e2 + e3 * e3;
                *(float4*)(out + row * D + kb) = make_float4(q0, q1, q2, q3);
            }
        }
    }

    // fused exact rescan: this wave handles its own 32-row bitmap word.
    // Exact numpy-order pipeline; lane handles 8 columns (j = lane + 64m).
    unsigned int fmask = flagbits[w];
    if (fmask) {
#pragma clang fp contract(off)
        float bn[8];
        #pragma unroll
        for (int m = 0; m < 8; ++m) bn[m] = 0.f;
        for (int k = 0; k < D; ++k) {
            const float* crow = cb + k * K + lane;
            #pragma unroll
            for (int m = 0; m < 8; ++m) {
                float c = crow[m * 64];
                bn[m] = bn[m] + c * c;
            }
        }
        while (fmask) {
            int b = __builtin_ctz(fmask);
            fmask &= fmask - 1;
            int row = rowBase + b;
            const float* xr = x + (size_t)row * D;
            // A = np.sum(x**2, axis=1): pairwise n=64 emulation
            float A0;
            {
                float rr[8];
                #pragma unroll
                for (int l = 0; l < 8; ++l) rr[l] = xr[l] * xr[l];
                #pragma unroll
                for (int m = 1; m < 8; ++m)
                    #pragma unroll
                    for (int l = 0; l < 8; ++l) {
                        float q = xr[8 * m + l] * xr[8 * m + l];
                        rr[l] = rr[l] + q;
                    }
                A0 = ((rr[0] + rr[1]) + (rr[2] + rr[3])) + ((rr[4] + rr[5]) + (rr[6] + rr[7]));
            }
            float a[8];
            #pragma unroll
            for (int m = 0; m < 8; ++m) a[m] = 0.f;
            for (int k = 0; k < D; ++k) {
                float xk = xr[k];
                const float* crow = cb + k * K + lane;
                #pragma unroll
                for (int m = 0; m < 8; ++m)
                    a[m] = fmaf(xk, crow[m * 64], a[m]);   // sequential-k fma chain
            }
            float db = INFINITY; int jb = 0x7fffffff;
            #pragma unroll
            for (int m = 0; m < 8; ++m) {
                float s = A0 + bn[m];
                float t2 = 2.0f * a[m];
                float d = s - t2;                  // fl(fl(A+B) - fl(2M))
                int j = lane + (m << 6);
                if (d < db) { db = d; jb = j; }
            }
            for (int s = 1; s < 64; s <<= 1) {     // first-index global argmin
                float od = __shfl_xor(db, s);
                int oj = __shfl_xor(jb, s);
                if ((od < db) || (od == db && oj < jb)) { db = od; jb = oj; }
            }
            float q = cb[lane * K + jb];
            out[(size_t)row * D + lane] = q;
            float e = q - xr[lane];
            lsum += e * e;
        }
    }

    #pragma unroll
    for (int off = 32; off > 0; off >>= 1) lsum += __shfl_down(lsum, off);
    if (lane == 0) wavesum[w] = lsum;
    __syncthreads();
    if (tid == 0) {
        double tot = (double)wavesum[0] + (double)wavesum[1]
                   + (double)wavesum[2] + (double)wavesum[3];
        atomicAdd(loss_acc, tot);
        __threadfence();
        unsigned int my = atomicAdd(ticket, 1u);
        if (my == (unsigned int)(gridDim.x - 1)) {
            // last block: all prior loss adds are ordered before their tickets
            double total = atomicAdd(loss_acc, 0.0);
            out[NELEM] = (float)(total * (1.25 / (double)NELEM));  // (1+beta)*mean
        }
    }
}

extern "C" void kernel_launch(void* const* d_in, const int* in_sizes, int n_in,
                              void* d_out, int out_size, void* d_ws, size_t ws_size,
                              hipStream_t stream) {
    const float* x  = (const float*)d_in[0];   // [32,64,64,64] fp32
    const float* cb = (const float*)d_in[1];   // [64,512] fp32
    float* out = (float*)d_out;                // [8388608] out + [1] loss
    double* loss_acc     = (double*)d_ws;
    unsigned int* ticket = (unsigned int*)((char*)d_ws + 8);
    float* Bn        = (float*)((char*)d_ws + 4096);
    _Float16* gH     = (_Float16*)((char*)d_ws + 8192);
    _Float16* gL     = (_Float16*)((char*)d_ws + 73728);

    vq_setup<<<64, 512, 0, stream>>>(cb, gH, gL, Bn, (unsigned long long*)d_ws);
    vq_main<<<NBLK, 256, 0, stream>>>(x, cb, gH, gL, Bn, out, loss_acc, ticket);
}

// Round 5
// 189.226 us; speedup vs baseline: 1.4820x; 1.0926x over previous
//
#include <hip/hip_runtime.h>
#include <math.h>

#define D 64
#define K 512
#define ROWS 131072       // 32*64*64
#define NELEM (ROWS * D)  // 8388608
#define TGAP 64.0f        // flag threshold in 2^20-scaled units (= 6.1e-5 unscaled)
#define FLAGBIT (1 << 30)

typedef _Float16 half8 __attribute__((ext_vector_type(8)));
typedef float floatx4 __attribute__((ext_vector_type(4)));

// ws layout (bytes):
//   [0,8)            double loss accumulator (rescan only)
//   [4096,6144)      float  Bn20[512]    column norms * 2^20 (numpy order, exact scale)
//   [8192,73728)     _Float16 gH[32768]  hi B-fragments, MFMA fragment order
//   [73728,139264)   _Float16 gL[32768]  lo B-fragments
//   [139264,155648)  uint32 bitmap[4096] flagged-row bitmap (1 bit per row)
//   [155648,159744)  double lpart[512]   per-block loss partials (plain stores)

// ---------------------------------------------------------------------------
// Setup: codebook -> scaled fp16 hi/lo in B-fragment order (global), + norms,
// + zero the loss accumulator (replaces the hipMemsetAsync launch).
// frag layout: half index = (((n>>4)*2 + (k>>5))*64 + ((k>>3)&3)*16 + (n&15))*8 + (k&7)
// ---------------------------------------------------------------------------
__global__ __launch_bounds__(512) void vq_setup(const float* __restrict__ cb,
                                                _Float16* __restrict__ gH,
                                                _Float16* __restrict__ gL,
                                                float* __restrict__ Bn,
                                                unsigned long long* __restrict__ zws) {
    int idx = blockIdx.x * 512 + threadIdx.x;   // 64 blocks x 512 = 32768
    int k = idx >> 9, n = idx & 511;
    float c = cb[idx];
    float t = c * 4096.0f;                      // 2^12, exact
    _Float16 ch = (_Float16)t;
    float r = t - (float)ch;                    // exact
    _Float16 cl = (_Float16)(r * 4096.0f);      // scale 2^24
    int off = (((n >> 4) * 2 + (k >> 5)) * 64 + ((k >> 3) & 3) * 16 + (n & 15)) * 8 + (k & 7);
    gH[off] = ch;
    gL[off] = cl;
    if (blockIdx.x == 1 && threadIdx.x < 2) zws[threadIdx.x] = 0ull;  // loss_acc
    if (blockIdx.x == 0) {
#pragma clang fp contract(off)
        int j = threadIdx.x;
        float b = 0.f;
        for (int kk = 0; kk < D; ++kk) { float cc = cb[kk * K + j]; b = b + cc * cc; }
        Bn[j] = b * 0x1p20f;                    // exact power-of-2 scale
    }
}

// ---------------------------------------------------------------------------
// Main: MFMA filter, 256 thr = 4 waves, 64 rows/wave (4 tiles of 16).
// Identical to the proven 74us/124-VGPR version EXCEPT the loss epilogue:
// plain store of the block partial to lpart[blockIdx.x] instead of a
// device-scope atomicAdd on one address (512 contended f64 atomics were
// the serialized tail theory for ~50us of the 74).
// ---------------------------------------------------------------------------
__global__ __launch_bounds__(256, 2) void vq_main(const float* __restrict__ x,
                                                  const float* __restrict__ cb,
                                                  const _Float16* __restrict__ gH,
                                                  const _Float16* __restrict__ gL,
                                                  const float* __restrict__ Bn,
                                                  float* __restrict__ out,
                                                  double* __restrict__ lpart,
                                                  unsigned int* __restrict__ bitmap) {
    __shared__ float ldsB[K];
    __shared__ int rowinfo[4][64];
    __shared__ unsigned int flagbits[8];
    __shared__ float wavesum[4];

    const int tid = threadIdx.x;
    const int lane = tid & 63;
    const int w = tid >> 6;
    const int quad = lane >> 4;
    const int nn = lane & 15;

    ldsB[tid] = Bn[tid];
    ldsB[tid + 256] = Bn[tid + 256];
    if (tid < 8) flagbits[tid] = 0;

    const int rowBase = blockIdx.x * 256 + w * 64;

    // A-fragments: lane holds A[m=nn][k=quad*8+j] per k-half s, scaled hi/lo
    half8 xh[4][2], xl[4][2];
    #pragma unroll
    for (int tt = 0; tt < 4; ++tt) {
        #pragma unroll
        for (int s = 0; s < 2; ++s) {
            const float* xp = x + (size_t)(rowBase + tt * 16 + nn) * D + s * 32 + quad * 8;
            float4 v0 = *(const float4*)xp;
            float4 v1 = *(const float4*)(xp + 4);
            float vv[8] = {v0.x, v0.y, v0.z, v0.w, v1.x, v1.y, v1.z, v1.w};
            #pragma unroll
            for (int j = 0; j < 8; ++j) {
                float t = vv[j] * 256.0f;        // 2^8, exact
                _Float16 h = (_Float16)t;
                float r = t - (float)h;          // exact
                xh[tt][s][j] = h;
                xl[tt][s][j] = (_Float16)(r * 4096.0f);  // scale 2^20
            }
        }
    }
    __syncthreads();

    float m1[4][4], m2[4][4];
    int   i1[4][4];
    #pragma unroll
    for (int tt = 0; tt < 4; ++tt)
        #pragma unroll
        for (int r = 0; r < 4; ++r) { m1[tt][r] = INFINITY; m2[tt][r] = INFINITY; i1[tt][r] = 0; }

    const half8* bHp = (const half8*)gH;
    const half8* bLp = (const half8*)gL;

    #pragma unroll 2
    for (int t = 0; t < 32; ++t) {
        half8 bh0 = bHp[(t * 2 + 0) * 64 + lane];   // coalesced 16B/lane
        half8 bl0 = bLp[(t * 2 + 0) * 64 + lane];
        half8 bh1 = bHp[(t * 2 + 1) * 64 + lane];
        half8 bl1 = bLp[(t * 2 + 1) * 64 + lane];
        int col = t * 16 + nn;
        float Bj = ldsB[col];                       // B*2^20
        #pragma unroll
        for (int tt = 0; tt < 4; ++tt) {
            floatx4 a1 = {0.f, 0.f, 0.f, 0.f};
            floatx4 a2 = {0.f, 0.f, 0.f, 0.f};
            a2 = __builtin_amdgcn_mfma_f32_16x16x32_f16(xl[tt][0], bh0, a2, 0, 0, 0);
            a2 = __builtin_amdgcn_mfma_f32_16x16x32_f16(xh[tt][0], bl0, a2, 0, 0, 0);
            a1 = __builtin_amdgcn_mfma_f32_16x16x32_f16(xh[tt][0], bh0, a1, 0, 0, 0);
            a2 = __builtin_amdgcn_mfma_f32_16x16x32_f16(xl[tt][1], bh1, a2, 0, 0, 0);
            a2 = __builtin_amdgcn_mfma_f32_16x16x32_f16(xh[tt][1], bl1, a2, 0, 0, 0);
            a1 = __builtin_amdgcn_mfma_f32_16x16x32_f16(xh[tt][1], bh1, a1, 0, 0, 0);
            #pragma unroll
            for (int r = 0; r < 4; ++r) {
                float macc = fmaf(0x1p-12f, a2[r], a1[r]);   // M * 2^20
                float g = fmaf(-2.0f, macc, Bj);             // (B - 2M) * 2^20
                float old1 = m1[tt][r];
                bool c1 = g < old1;
                m2[tt][r] = fminf(fmaxf(g, old1), m2[tt][r]);
                m1[tt][r] = c1 ? g : old1;
                i1[tt][r] = c1 ? col : i1[tt][r];            // strict <, j ascending
            }
        }
    }

    // merge best-2 across the 16 col-lanes (butterfly over low 4 lane bits)
    #pragma unroll
    for (int dlt = 1; dlt < 16; dlt <<= 1) {
        #pragma unroll
        for (int tt = 0; tt < 4; ++tt)
            #pragma unroll
            for (int r = 0; r < 4; ++r) {
                float om1 = __shfl_xor(m1[tt][r], dlt);
                int   oi1 = __shfl_xor(i1[tt][r], dlt);
                float om2 = __shfl_xor(m2[tt][r], dlt);
                bool ofirst = (om1 < m1[tt][r]) || (om1 == m1[tt][r] && oi1 < i1[tt][r]);
                float l1   = ofirst ? m1[tt][r] : om1;
                float cand = ofirst ? om2 : m2[tt][r];
                m1[tt][r] = ofirst ? om1 : m1[tt][r];
                i1[tt][r] = ofirst ? oi1 : i1[tt][r];
                m2[tt][r] = fminf(cand, l1);
            }
    }

    // record results; flagged rows -> LDS bitmap bits
    if (nn == 0) {
        #pragma unroll
        for (int tt = 0; tt < 4; ++tt)
            #pragma unroll
            for (int r = 0; r < 4; ++r) {
                int rl = tt * 16 + quad * 4 + r;
                bool flg = (m2[tt][r] - m1[tt][r]) < TGAP;
                rowinfo[w][rl] = i1[tt][r] | (flg ? FLAGBIT : 0);
                if (flg) atomicOr(&flagbits[(w * 64 + rl) >> 5], 1u << ((w * 64 + rl) & 31));
            }
    }
    __syncthreads();
    if (tid < 8) bitmap[blockIdx.x * 8 + tid] = flagbits[tid];   // block-owned, no pre-zero

    // coalesced output + loss for certain rows
    float lsum = 0.f;
    #pragma unroll
    for (int tt = 0; tt < 4; ++tt) {
        #pragma unroll
        for (int p = 0; p < 4; ++p) {
            int rl = tt * 16 + p * 4 + quad;
            int info = rowinfo[w][rl];
            if (!(info & FLAGBIT)) {
                int j = info & 511;
                int kb = nn * 4;
                float q0 = cb[(kb + 0) * K + j];
                float q1 = cb[(kb + 1) * K + j];
                float q2 = cb[(kb + 2) * K + j];
                float q3 = cb[(kb + 3) * K + j];
                size_t row = (size_t)rowBase + rl;
                float4 xv = *(const float4*)(x + row * D + kb);
                float e0 = q0 - xv.x, e1 = q1 - xv.y, e2 = q2 - xv.z, e3 = q3 - xv.w;
                lsum += e0 * e0 + e1 * e1 + e2 * e2 + e3 * e3;
                *(float4*)(out + row * D + kb) = make_float4(q0, q1, q2, q3);
            }
        }
    }
    #pragma unroll
    for (int off = 32; off > 0; off >>= 1) lsum += __shfl_down(lsum, off);
    if (lane == 0) wavesum[w] = lsum;
    __syncthreads();
    if (tid == 0) {
        double tot = (double)wavesum[0] + (double)wavesum[1]
                   + (double)wavesum[2] + (double)wavesum[3];
        lpart[blockIdx.x] = tot;                 // plain store: no contention
    }
}

// ---------------------------------------------------------------------------
// Rescan: exact numpy-order pipeline for flagged rows. One wave per 64-row
// bitmap span; lane handles 8 columns (j = lane + 64m). One atomic per wave,
// and only for the ~tens of waves that own a flagged row (no contention).
// ---------------------------------------------------------------------------
__global__ __launch_bounds__(256) void vq_rescan(const float* __restrict__ x,
                                                 const float* __restrict__ cb,
                                                 float* __restrict__ out,
                                                 double* __restrict__ loss_acc,
                                                 const unsigned int* __restrict__ bitmap) {
#pragma clang fp contract(off)
    const int lane = threadIdx.x & 63;
    const int gwave = blockIdx.x * 4 + (threadIdx.x >> 6);   // 0..2047

    unsigned int w0 = bitmap[gwave * 2 + 0];
    unsigned int w1 = bitmap[gwave * 2 + 1];
    unsigned long long mask = ((unsigned long long)w1 << 32) | w0;
    float wloss = 0.f;
    if (mask) {
        // numpy-order column norms for my 8 columns (hoisted across rows)
        float bn[8];
        #pragma unroll
        for (int m = 0; m < 8; ++m) bn[m] = 0.f;
        for (int k = 0; k < D; ++k) {
            const float* crow = cb + k * K + lane;
            #pragma unroll
            for (int m = 0; m < 8; ++m) {
                float c = crow[m * 64];
                bn[m] = bn[m] + c * c;
            }
        }
        while (mask) {
            int b = __builtin_ctzll(mask);
            mask &= mask - 1;
            int row = gwave * 64 + b;
            const float* xr = x + (size_t)row * D;
            // A = np.sum(x**2, axis=1): pairwise n=64 emulation
            float A0;
            {
                float rr[8];
                #pragma unroll
                for (int l = 0; l < 8; ++l) rr[l] = xr[l] * xr[l];
                #pragma unroll
                for (int m = 1; m < 8; ++m)
                    #pragma unroll
                    for (int l = 0; l < 8; ++l) {
                        float q = xr[8 * m + l] * xr[8 * m + l];
                        rr[l] = rr[l] + q;
                    }
                A0 = ((rr[0] + rr[1]) + (rr[2] + rr[3])) + ((rr[4] + rr[5]) + (rr[6] + rr[7]));
            }
            float a[8];
            #pragma unroll
            for (int m = 0; m < 8; ++m) a[m] = 0.f;
            for (int k = 0; k < D; ++k) {
                float xk = xr[k];
                const float* crow = cb + k * K + lane;
                #pragma unroll
                for (int m = 0; m < 8; ++m)
                    a[m] = fmaf(xk, crow[m * 64], a[m]);   // sequential-k fma chain
            }
            float db = INFINITY; int jb = 0x7fffffff;
            #pragma unroll
            for (int m = 0; m < 8; ++m) {
                float s = A0 + bn[m];
                float t2 = 2.0f * a[m];
                float d = s - t2;                  // fl(fl(A+B) - fl(2M))
                int j = lane + (m << 6);
                if (d < db) { db = d; jb = j; }
            }
            for (int s = 1; s < 64; s <<= 1) {     // first-index global argmin
                float od = __shfl_xor(db, s);
                int oj = __shfl_xor(jb, s);
                if ((od < db) || (od == db && oj < jb)) { db = od; jb = oj; }
            }
            float q = cb[lane * K + jb];
            out[(size_t)row * D + lane] = q;
            float e = q - xr[lane];
            wloss += e * e;
        }
    }
    #pragma unroll
    for (int off = 32; off > 0; off >>= 1) wloss += __shfl_down(wloss, off);
    if (lane == 0 && wloss != 0.f) atomicAdd(loss_acc, (double)wloss);
}

// ---------------------------------------------------------------------------
// Finalize: tree-sum the 512 block partials + rescan accumulator.
// ---------------------------------------------------------------------------
__global__ __launch_bounds__(256) void vq_finalize(const double* __restrict__ lpart,
                                                   const double* __restrict__ acc,
                                                   float* __restrict__ out) {
    __shared__ double ws4[4];
    int tid = threadIdx.x;
    double s = lpart[tid] + lpart[tid + 256];
    #pragma unroll
    for (int off = 32; off > 0; off >>= 1) s += __shfl_down(s, off);
    if ((tid & 63) == 0) ws4[tid >> 6] = s;
    __syncthreads();
    if (tid == 0) {
        double tot = ws4[0] + ws4[1] + ws4[2] + ws4[3] + acc[0];
        // loss = (1 + beta) * mean((q - x)^2), beta = 0.25
        out[NELEM] = (float)(tot * (1.25 / (double)NELEM));
    }
}

extern "C" void kernel_launch(void* const* d_in, const int* in_sizes, int n_in,
                              void* d_out, int out_size, void* d_ws, size_t ws_size,
                              hipStream_t stream) {
    const float* x  = (const float*)d_in[0];   // [32,64,64,64] fp32
    const float* cb = (const float*)d_in[1];   // [64,512] fp32
    float* out = (float*)d_out;                // [8388608] out + [1] loss
    double* loss_acc = (double*)d_ws;
    float* Bn        = (float*)((char*)d_ws + 4096);
    _Float16* gH     = (_Float16*)((char*)d_ws + 8192);
    _Float16* gL     = (_Float16*)((char*)d_ws + 73728);
    unsigned int* bm = (unsigned int*)((char*)d_ws + 139264);
    double* lpart    = (double*)((char*)d_ws + 155648);

    vq_setup<<<64, 512, 0, stream>>>(cb, gH, gL, Bn, (unsigned long long*)d_ws);
    vq_main<<<ROWS / 256, 256, 0, stream>>>(x, cb, gH, gL, Bn, out, lpart, bm);
    vq_rescan<<<512, 256, 0, stream>>>(x, cb, out, loss_acc, bm);
    vq_finalize<<<1, 256, 0, stream>>>(lpart, loss_acc, out);
}

// Round 6
// 185.081 us; speedup vs baseline: 1.5151x; 1.0224x over previous
//
#include <hip/hip_runtime.h>
#include <math.h>

#define D 64
#define K 512
#define ROWS 131072       // 32*64*64
#define NELEM (ROWS * D)  // 8388608
#define TGAP 64.0f        // flag threshold in 2^20-scaled units (= 6.1e-5 unscaled)
#define FLAGBIT (1 << 30)

typedef _Float16 half8 __attribute__((ext_vector_type(8)));
typedef float floatx4 __attribute__((ext_vector_type(4)));

// ws layout (bytes):
//   [0,8)            double loss accumulator (rescan only)
//   [4096,6144)      float  Bn20[512]    column norms * 2^20 (numpy order, exact scale)
//   [8192,73728)     _Float16 gH[32768]  hi B-fragments, MFMA fragment order
//   [73728,139264)   _Float16 gL[32768]  lo B-fragments
//   [139264,155648)  uint32 bitmap[4096] flagged-row bitmap (1 bit per row)
//   [155648,159744)  double lpart[512]   per-block loss partials (plain stores)

// ---------------------------------------------------------------------------
// Setup: codebook -> scaled fp16 hi/lo in B-fragment order (global), + norms,
// + zero the loss accumulator (replaces the hipMemsetAsync launch).
// frag layout: half index = (((n>>4)*2 + (k>>5))*64 + ((k>>3)&3)*16 + (n&15))*8 + (k&7)
// ---------------------------------------------------------------------------
__global__ __launch_bounds__(512) void vq_setup(const float* __restrict__ cb,
                                                _Float16* __restrict__ gH,
                                                _Float16* __restrict__ gL,
                                                float* __restrict__ Bn,
                                                unsigned long long* __restrict__ zws) {
    int idx = blockIdx.x * 512 + threadIdx.x;   // 64 blocks x 512 = 32768
    int k = idx >> 9, n = idx & 511;
    float c = cb[idx];
    float t = c * 4096.0f;                      // 2^12, exact
    _Float16 ch = (_Float16)t;
    float r = t - (float)ch;                    // exact
    _Float16 cl = (_Float16)(r * 4096.0f);      // scale 2^24
    int off = (((n >> 4) * 2 + (k >> 5)) * 64 + ((k >> 3) & 3) * 16 + (n & 15)) * 8 + (k & 7);
    gH[off] = ch;
    gL[off] = cl;
    if (blockIdx.x == 1 && threadIdx.x < 2) zws[threadIdx.x] = 0ull;  // loss_acc
    if (blockIdx.x == 0) {
#pragma clang fp contract(off)
        int j = threadIdx.x;
        float b = 0.f;
        for (int kk = 0; kk < D; ++kk) { float cc = cb[kk * K + j]; b = b + cc * cc; }
        Bn[j] = b * 0x1p20f;                    // exact power-of-2 scale
    }
}

// ---------------------------------------------------------------------------
// Main: MFMA filter, 256 thr = 4 waves, 64 rows/wave (4 tiles of 16).
// Proven 74us/124-VGPR hot-loop structure, two changes:
//  (1) B-fragments staged global->LDS via global_load_lds (16B), double-
//      buffered: wave w DMAs part w of tile t+1 while all 4 waves ds_read
//      tile t. One __syncthreads per iteration = the vmcnt(0)+barrier
//      handoff. Removes the 4x-redundant per-wave L2 loads (~250cyc dep)
//      in favor of LDS reads (~100cyc) with prefetch hiding the L2 trip.
//  (2) fmed3 second-best update (6 -> 5 VALU ops/value, R1-R4-proven).
// ---------------------------------------------------------------------------
__global__ __launch_bounds__(256, 2) void vq_main(const float* __restrict__ x,
                                                  const float* __restrict__ cb,
                                                  const _Float16* __restrict__ gH,
                                                  const _Float16* __restrict__ gL,
                                                  const float* __restrict__ Bn,
                                                  float* __restrict__ out,
                                                  double* __restrict__ lpart,
                                                  unsigned int* __restrict__ bitmap) {
    __shared__ float ldsB[K];
    __shared__ half8 bstage[2][4][64];     // 2 buf x {H-even,L-even,H-odd,L-odd} x 64 lanes, 8 KB
    __shared__ int rowinfo[4][64];
    __shared__ unsigned int flagbits[8];
    __shared__ float wavesum[4];

    const int tid = threadIdx.x;
    const int lane = tid & 63;
    const int w = tid >> 6;
    const int quad = lane >> 4;
    const int nn = lane & 15;

    ldsB[tid] = Bn[tid];
    ldsB[tid + 256] = Bn[tid + 256];
    if (tid < 8) flagbits[tid] = 0;

    const int rowBase = blockIdx.x * 256 + w * 64;

    // A-fragments: lane holds A[m=nn][k=quad*8+j] per k-half s, scaled hi/lo
    half8 xh[4][2], xl[4][2];
    #pragma unroll
    for (int tt = 0; tt < 4; ++tt) {
        #pragma unroll
        for (int s = 0; s < 2; ++s) {
            const float* xp = x + (size_t)(rowBase + tt * 16 + nn) * D + s * 32 + quad * 8;
            float4 v0 = *(const float4*)xp;
            float4 v1 = *(const float4*)(xp + 4);
            float vv[8] = {v0.x, v0.y, v0.z, v0.w, v1.x, v1.y, v1.z, v1.w};
            #pragma unroll
            for (int j = 0; j < 8; ++j) {
                float t = vv[j] * 256.0f;        // 2^8, exact
                _Float16 h = (_Float16)t;
                float r = t - (float)h;          // exact
                xh[tt][s][j] = h;
                xl[tt][s][j] = (_Float16)(r * 4096.0f);  // scale 2^20
            }
        }
    }

    // wave w stages part w: {w&1 ? gL : gH}, tile 2t + (w>>1). LDS dest is
    // wave-uniform base; HW writes lane l at base + l*16 (linear, matches read).
#define STAGE(buf, tt_) do {                                                        \
        const _Float16* gsrc = ((w & 1) ? gL : gH)                                  \
                             + ((((tt_) * 2 + (w >> 1)) * 64 + lane) * 8);          \
        __builtin_amdgcn_global_load_lds(                                           \
            (const __attribute__((address_space(1))) void*)gsrc,                    \
            (__attribute__((address_space(3))) void*)&bstage[buf][w][0], 16, 0, 0); \
    } while (0)

    STAGE(0, 0);
    __syncthreads();   // covers ldsB writes + prologue stage (vmcnt drain)

    float m1[4][4], m2[4][4];
    int   i1[4][4];
    #pragma unroll
    for (int tt = 0; tt < 4; ++tt)
        #pragma unroll
        for (int r = 0; r < 4; ++r) { m1[tt][r] = INFINITY; m2[tt][r] = INFINITY; i1[tt][r] = 0; }

    #pragma unroll 2
    for (int t = 0; t < 32; ++t) {
        const int cur = t & 1;
        if (t < 31) STAGE(cur ^ 1, t + 1);          // prefetch next tile
        half8 bh0 = bstage[cur][0][lane];           // ds_read_b128, conflict-free
        half8 bl0 = bstage[cur][1][lane];
        half8 bh1 = bstage[cur][2][lane];
        half8 bl1 = bstage[cur][3][lane];
        int col = t * 16 + nn;
        float Bj = ldsB[col];                       // B*2^20
        #pragma unroll
        for (int tt = 0; tt < 4; ++tt) {
            floatx4 a1 = {0.f, 0.f, 0.f, 0.f};
            floatx4 a2 = {0.f, 0.f, 0.f, 0.f};
            a2 = __builtin_amdgcn_mfma_f32_16x16x32_f16(xl[tt][0], bh0, a2, 0, 0, 0);
            a2 = __builtin_amdgcn_mfma_f32_16x16x32_f16(xh[tt][0], bl0, a2, 0, 0, 0);
            a1 = __builtin_amdgcn_mfma_f32_16x16x32_f16(xh[tt][0], bh0, a1, 0, 0, 0);
            a2 = __builtin_amdgcn_mfma_f32_16x16x32_f16(xl[tt][1], bh1, a2, 0, 0, 0);
            a2 = __builtin_amdgcn_mfma_f32_16x16x32_f16(xh[tt][1], bl1, a2, 0, 0, 0);
            a1 = __builtin_amdgcn_mfma_f32_16x16x32_f16(xh[tt][1], bh1, a1, 0, 0, 0);
            #pragma unroll
            for (int r = 0; r < 4; ++r) {
                float macc = fmaf(0x1p-12f, a2[r], a1[r]);   // M * 2^20
                float g = fmaf(-2.0f, macc, Bj);             // (B - 2M) * 2^20
                float old1 = m1[tt][r];
                // new 2nd-best of {old1, old2, g} = median of the three
                m2[tt][r] = __builtin_amdgcn_fmed3f(g, old1, m2[tt][r]);
                bool c1 = g < old1;
                m1[tt][r] = c1 ? g : old1;
                i1[tt][r] = c1 ? col : i1[tt][r];            // strict <, j ascending
            }
        }
        __syncthreads();   // vmcnt(0)+barrier: next tile landed, this buf free
    }
#undef STAGE

    // merge best-2 across the 16 col-lanes (butterfly over low 4 lane bits)
    #pragma unroll
    for (int dlt = 1; dlt < 16; dlt <<= 1) {
        #pragma unroll
        for (int tt = 0; tt < 4; ++tt)
            #pragma unroll
            for (int r = 0; r < 4; ++r) {
                float om1 = __shfl_xor(m1[tt][r], dlt);
                int   oi1 = __shfl_xor(i1[tt][r], dlt);
                float om2 = __shfl_xor(m2[tt][r], dlt);
                bool ofirst = (om1 < m1[tt][r]) || (om1 == m1[tt][r] && oi1 < i1[tt][r]);
                float l1   = ofirst ? m1[tt][r] : om1;
                float cand = ofirst ? om2 : m2[tt][r];
                m1[tt][r] = ofirst ? om1 : m1[tt][r];
                i1[tt][r] = ofirst ? oi1 : i1[tt][r];
                m2[tt][r] = fminf(cand, l1);
            }
    }

    // record results; flagged rows -> LDS bitmap bits
    if (nn == 0) {
        #pragma unroll
        for (int tt = 0; tt < 4; ++tt)
            #pragma unroll
            for (int r = 0; r < 4; ++r) {
                int rl = tt * 16 + quad * 4 + r;
                bool flg = (m2[tt][r] - m1[tt][r]) < TGAP;
                rowinfo[w][rl] = i1[tt][r] | (flg ? FLAGBIT : 0);
                if (flg) atomicOr(&flagbits[(w * 64 + rl) >> 5], 1u << ((w * 64 + rl) & 31));
            }
    }
    __syncthreads();
    if (tid < 8) bitmap[blockIdx.x * 8 + tid] = flagbits[tid];   // block-owned, no pre-zero

    // coalesced output + loss for certain rows
    float lsum = 0.f;
    #pragma unroll
    for (int tt = 0; tt < 4; ++tt) {
        #pragma unroll
        for (int p = 0; p < 4; ++p) {
            int rl = tt * 16 + p * 4 + quad;
            int info = rowinfo[w][rl];
            if (!(info & FLAGBIT)) {
                int j = info & 511;
                int kb = nn * 4;
                float q0 = cb[(kb + 0) * K + j];
                float q1 = cb[(kb + 1) * K + j];
                float q2 = cb[(kb + 2) * K + j];
                float q3 = cb[(kb + 3) * K + j];
                size_t row = (size_t)rowBase + rl;
                float4 xv = *(const float4*)(x + row * D + kb);
                float e0 = q0 - xv.x, e1 = q1 - xv.y, e2 = q2 - xv.z, e3 = q3 - xv.w;
                lsum += e0 * e0 + e1 * e1 + e2 * e2 + e3 * e3;
                *(float4*)(out + row * D + kb) = make_float4(q0, q1, q2, q3);
            }
        }
    }
    #pragma unroll
    for (int off = 32; off > 0; off >>= 1) lsum += __shfl_down(lsum, off);
    if (lane == 0) wavesum[w] = lsum;
    __syncthreads();
    if (tid == 0) {
        double tot = (double)wavesum[0] + (double)wavesum[1]
                   + (double)wavesum[2] + (double)wavesum[3];
        lpart[blockIdx.x] = tot;                 // plain store: no contention
    }
}

// ---------------------------------------------------------------------------
// Rescan: exact numpy-order pipeline for flagged rows. One wave per 64-row
// bitmap span; lane handles 8 columns (j = lane + 64m). One atomic per wave,
// and only for the ~tens of waves that own a flagged row (no contention).
// ---------------------------------------------------------------------------
__global__ __launch_bounds__(256) void vq_rescan(const float* __restrict__ x,
                                                 const float* __restrict__ cb,
                                                 float* __restrict__ out,
                                                 double* __restrict__ loss_acc,
                                                 const unsigned int* __restrict__ bitmap) {
#pragma clang fp contract(off)
    const int lane = threadIdx.x & 63;
    const int gwave = blockIdx.x * 4 + (threadIdx.x >> 6);   // 0..2047

    unsigned int w0 = bitmap[gwave * 2 + 0];
    unsigned int w1 = bitmap[gwave * 2 + 1];
    unsigned long long mask = ((unsigned long long)w1 << 32) | w0;
    float wloss = 0.f;
    if (mask) {
        // numpy-order column norms for my 8 columns (hoisted across rows)
        float bn[8];
        #pragma unroll
        for (int m = 0; m < 8; ++m) bn[m] = 0.f;
        for (int k = 0; k < D; ++k) {
            const float* crow = cb + k * K + lane;
            #pragma unroll
            for (int m = 0; m < 8; ++m) {
                float c = crow[m * 64];
                bn[m] = bn[m] + c * c;
            }
        }
        while (mask) {
            int b = __builtin_ctzll(mask);
            mask &= mask - 1;
            int row = gwave * 64 + b;
            const float* xr = x + (size_t)row * D;
            // A = np.sum(x**2, axis=1): pairwise n=64 emulation
            float A0;
            {
                float rr[8];
                #pragma unroll
                for (int l = 0; l < 8; ++l) rr[l] = xr[l] * xr[l];
                #pragma unroll
                for (int m = 1; m < 8; ++m)
                    #pragma unroll
                    for (int l = 0; l < 8; ++l) {
                        float q = xr[8 * m + l] * xr[8 * m + l];
                        rr[l] = rr[l] + q;
                    }
                A0 = ((rr[0] + rr[1]) + (rr[2] + rr[3])) + ((rr[4] + rr[5]) + (rr[6] + rr[7]));
            }
            float a[8];
            #pragma unroll
            for (int m = 0; m < 8; ++m) a[m] = 0.f;
            for (int k = 0; k < D; ++k) {
                float xk = xr[k];
                const float* crow = cb + k * K + lane;
                #pragma unroll
                for (int m = 0; m < 8; ++m)
                    a[m] = fmaf(xk, crow[m * 64], a[m]);   // sequential-k fma chain
            }
            float db = INFINITY; int jb = 0x7fffffff;
            #pragma unroll
            for (int m = 0; m < 8; ++m) {
                float s = A0 + bn[m];
                float t2 = 2.0f * a[m];
                float d = s - t2;                  // fl(fl(A+B) - fl(2M))
                int j = lane + (m << 6);
                if (d < db) { db = d; jb = j; }
            }
            for (int s = 1; s < 64; s <<= 1) {     // first-index global argmin
                float od = __shfl_xor(db, s);
                int oj = __shfl_xor(jb, s);
                if ((od < db) || (od == db && oj < jb)) { db = od; jb = oj; }
            }
            float q = cb[lane * K + jb];
            out[(size_t)row * D + lane] = q;
            float e = q - xr[lane];
            wloss += e * e;
        }
    }
    #pragma unroll
    for (int off = 32; off > 0; off >>= 1) wloss += __shfl_down(wloss, off);
    if (lane == 0 && wloss != 0.f) atomicAdd(loss_acc, (double)wloss);
}

// ---------------------------------------------------------------------------
// Finalize: tree-sum the 512 block partials + rescan accumulator.
// ---------------------------------------------------------------------------
__global__ __launch_bounds__(256) void vq_finalize(const double* __restrict__ lpart,
                                                   const double* __restrict__ acc,
                                                   float* __restrict__ out) {
    __shared__ double ws4[4];
    int tid = threadIdx.x;
    double s = lpart[tid] + lpart[tid + 256];
    #pragma unroll
    for (int off = 32; off > 0; off >>= 1) s += __shfl_down(s, off);
    if ((tid & 63) == 0) ws4[tid >> 6] = s;
    __syncthreads();
    if (tid == 0) {
        double tot = ws4[0] + ws4[1] + ws4[2] + ws4[3] + acc[0];
        // loss = (1 + beta) * mean((q - x)^2), beta = 0.25
        out[NELEM] = (float)(tot * (1.25 / (double)NELEM));
    }
}

extern "C" void kernel_launch(void* const* d_in, const int* in_sizes, int n_in,
                              void* d_out, int out_size, void* d_ws, size_t ws_size,
                              hipStream_t stream) {
    const float* x  = (const float*)d_in[0];   // [32,64,64,64] fp32
    const float* cb = (const float*)d_in[1];   // [64,512] fp32
    float* out = (float*)d_out;                // [8388608] out + [1] loss
    double* loss_acc = (double*)d_ws;
    float* Bn        = (float*)((char*)d_ws + 4096);
    _Float16* gH     = (_Float16*)((char*)d_ws + 8192);
    _Float16* gL     = (_Float16*)((char*)d_ws + 73728);
    unsigned int* bm = (unsigned int*)((char*)d_ws + 139264);
    double* lpart    = (double*)((char*)d_ws + 155648);

    vq_setup<<<64, 512, 0, stream>>>(cb, gH, gL, Bn, (unsigned long long*)d_ws);
    vq_main<<<ROWS / 256, 256, 0, stream>>>(x, cb, gH, gL, Bn, out, lpart, bm);
    vq_rescan<<<512, 256, 0, stream>>>(x, cb, out, loss_acc, bm);
    vq_finalize<<<1, 256, 0, stream>>>(lpart, loss_acc, out);
}

// Round 7
// 182.275 us; speedup vs baseline: 1.5385x; 1.0154x over previous
//
#include <hip/hip_runtime.h>
#include <math.h>

#define D 64
#define K 512
#define ROWS 131072       // 32*64*64
#define NELEM (ROWS * D)  // 8388608
#define TGAP 64.0f        // flag threshold in 2^20-scaled units (= 6.1e-5 unscaled)
#define FLAGBIT (1 << 30)
#define RPB 128           // rows per block: 4 waves x 32 rows
#define NBLK (ROWS / RPB) // 1024 blocks -> 4 blocks/CU, 16 waves/CU

typedef _Float16 half8 __attribute__((ext_vector_type(8)));
typedef float floatx4 __attribute__((ext_vector_type(4)));

// ws layout (bytes):
//   [0,8)            double loss accumulator (rescan only)
//   [4096,6144)      float  Bn20[512]    column norms * 2^20 (numpy order, exact scale)
//   [8192,73728)     _Float16 gH[32768]  hi B-fragments, MFMA fragment order
//   [73728,139264)   _Float16 gL[32768]  lo B-fragments
//   [139264,155648)  uint32 bitmap[4096] flagged-row bitmap (1 bit per row)
//   [155648,163840)  double lpart[1024]  per-block loss partials (plain stores)

// ---------------------------------------------------------------------------
// Setup: codebook -> scaled fp16 hi/lo in B-fragment order (global), + norms,
// + zero the loss accumulator (replaces the hipMemsetAsync launch).
// frag layout: half index = (((n>>4)*2 + (k>>5))*64 + ((k>>3)&3)*16 + (n&15))*8 + (k&7)
// ---------------------------------------------------------------------------
__global__ __launch_bounds__(512) void vq_setup(const float* __restrict__ cb,
                                                _Float16* __restrict__ gH,
                                                _Float16* __restrict__ gL,
                                                float* __restrict__ Bn,
                                                unsigned long long* __restrict__ zws) {
    int idx = blockIdx.x * 512 + threadIdx.x;   // 64 blocks x 512 = 32768
    int k = idx >> 9, n = idx & 511;
    float c = cb[idx];
    float t = c * 4096.0f;                      // 2^12, exact
    _Float16 ch = (_Float16)t;
    float r = t - (float)ch;                    // exact
    _Float16 cl = (_Float16)(r * 4096.0f);      // scale 2^24
    int off = (((n >> 4) * 2 + (k >> 5)) * 64 + ((k >> 3) & 3) * 16 + (n & 15)) * 8 + (k & 7);
    gH[off] = ch;
    gL[off] = cl;
    if (blockIdx.x == 1 && threadIdx.x < 2) zws[threadIdx.x] = 0ull;  // loss_acc
    if (blockIdx.x == 0) {
#pragma clang fp contract(off)
        int j = threadIdx.x;
        float b = 0.f;
        for (int kk = 0; kk < D; ++kk) { float cc = cb[kk * K + j]; b = b + cc * cc; }
        Bn[j] = b * 0x1p20f;                    // exact power-of-2 scale
    }
}

// ---------------------------------------------------------------------------
// Main: MFMA filter, 256 thr = 4 waves, 32 rows/wave (2 tiles of 16).
// R6 structure (LDS-staged B, double-buffered global_load_lds, fmed3)
// with halved per-wave rows -> 1024 blocks = 4 blocks/CU = 4 waves/SIMD.
// Live set ~75 regs (A-frags 32 + best2 state 24 + B 16) now FITS the
// allocator's tier targets (84/64) without the remat that sank R1 at this
// shape (its live set was ~130 pre-LDS-staging).
// ---------------------------------------------------------------------------
__global__ __launch_bounds__(256, 2) void vq_main(const float* __restrict__ x,
                                                  const float* __restrict__ cb,
                                                  const _Float16* __restrict__ gH,
                                                  const _Float16* __restrict__ gL,
                                                  const float* __restrict__ Bn,
                                                  float* __restrict__ out,
                                                  double* __restrict__ lpart,
                                                  unsigned int* __restrict__ bitmap) {
    __shared__ float ldsB[K];
    __shared__ half8 bstage[2][4][64];     // 2 buf x {H-even,L-even,H-odd,L-odd} x 64 lanes, 8 KB
    __shared__ int rowinfo[4][32];
    __shared__ unsigned int flagbits[4];
    __shared__ float wavesum[4];

    const int tid = threadIdx.x;
    const int lane = tid & 63;
    const int w = tid >> 6;
    const int quad = lane >> 4;
    const int nn = lane & 15;

    ldsB[tid] = Bn[tid];
    ldsB[tid + 256] = Bn[tid + 256];
    if (tid < 4) flagbits[tid] = 0;

    const int rowBase = blockIdx.x * RPB + w * 32;

    // A-fragments: lane holds A[m=nn][k=quad*8+j] per k-half s, scaled hi/lo
    half8 xh[2][2], xl[2][2];
    #pragma unroll
    for (int tt = 0; tt < 2; ++tt) {
        #pragma unroll
        for (int s = 0; s < 2; ++s) {
            const float* xp = x + (size_t)(rowBase + tt * 16 + nn) * D + s * 32 + quad * 8;
            float4 v0 = *(const float4*)xp;
            float4 v1 = *(const float4*)(xp + 4);
            float vv[8] = {v0.x, v0.y, v0.z, v0.w, v1.x, v1.y, v1.z, v1.w};
            #pragma unroll
            for (int j = 0; j < 8; ++j) {
                float t = vv[j] * 256.0f;        // 2^8, exact
                _Float16 h = (_Float16)t;
                float r = t - (float)h;          // exact
                xh[tt][s][j] = h;
                xl[tt][s][j] = (_Float16)(r * 4096.0f);  // scale 2^20
            }
        }
    }

    // wave w stages part w: {w&1 ? gL : gH}, tile 2t + (w>>1). LDS dest is
    // wave-uniform base; HW writes lane l at base + l*16 (linear, matches read).
#define STAGE(buf, tt_) do {                                                        \
        const _Float16* gsrc = ((w & 1) ? gL : gH)                                  \
                             + ((((tt_) * 2 + (w >> 1)) * 64 + lane) * 8);          \
        __builtin_amdgcn_global_load_lds(                                           \
            (const __attribute__((address_space(1))) void*)gsrc,                    \
            (__attribute__((address_space(3))) void*)&bstage[buf][w][0], 16, 0, 0); \
    } while (0)

    STAGE(0, 0);
    __syncthreads();   // covers ldsB writes + prologue stage (vmcnt drain)

    float m1[2][4], m2[2][4];
    int   i1[2][4];
    #pragma unroll
    for (int tt = 0; tt < 2; ++tt)
        #pragma unroll
        for (int r = 0; r < 4; ++r) { m1[tt][r] = INFINITY; m2[tt][r] = INFINITY; i1[tt][r] = 0; }

    #pragma unroll 2
    for (int t = 0; t < 32; ++t) {
        const int cur = t & 1;
        if (t < 31) STAGE(cur ^ 1, t + 1);          // prefetch next tile
        half8 bh0 = bstage[cur][0][lane];           // ds_read_b128, conflict-free
        half8 bl0 = bstage[cur][1][lane];
        half8 bh1 = bstage[cur][2][lane];
        half8 bl1 = bstage[cur][3][lane];
        int col = t * 16 + nn;
        float Bj = ldsB[col];                       // B*2^20
        #pragma unroll
        for (int tt = 0; tt < 2; ++tt) {
            floatx4 a1 = {0.f, 0.f, 0.f, 0.f};
            floatx4 a2 = {0.f, 0.f, 0.f, 0.f};
            a2 = __builtin_amdgcn_mfma_f32_16x16x32_f16(xl[tt][0], bh0, a2, 0, 0, 0);
            a2 = __builtin_amdgcn_mfma_f32_16x16x32_f16(xh[tt][0], bl0, a2, 0, 0, 0);
            a1 = __builtin_amdgcn_mfma_f32_16x16x32_f16(xh[tt][0], bh0, a1, 0, 0, 0);
            a2 = __builtin_amdgcn_mfma_f32_16x16x32_f16(xl[tt][1], bh1, a2, 0, 0, 0);
            a2 = __builtin_amdgcn_mfma_f32_16x16x32_f16(xh[tt][1], bl1, a2, 0, 0, 0);
            a1 = __builtin_amdgcn_mfma_f32_16x16x32_f16(xh[tt][1], bh1, a1, 0, 0, 0);
            #pragma unroll
            for (int r = 0; r < 4; ++r) {
                float macc = fmaf(0x1p-12f, a2[r], a1[r]);   // M * 2^20
                float g = fmaf(-2.0f, macc, Bj);             // (B - 2M) * 2^20
                float old1 = m1[tt][r];
                // new 2nd-best of {old1, old2, g} = median of the three
                m2[tt][r] = __builtin_amdgcn_fmed3f(g, old1, m2[tt][r]);
                bool c1 = g < old1;
                m1[tt][r] = c1 ? g : old1;
                i1[tt][r] = c1 ? col : i1[tt][r];            // strict <, j ascending
            }
        }
        __syncthreads();   // vmcnt(0)+barrier: next tile landed, this buf free
    }
#undef STAGE

    // merge best-2 across the 16 col-lanes (butterfly over low 4 lane bits)
    #pragma unroll
    for (int dlt = 1; dlt < 16; dlt <<= 1) {
        #pragma unroll
        for (int tt = 0; tt < 2; ++tt)
            #pragma unroll
            for (int r = 0; r < 4; ++r) {
                float om1 = __shfl_xor(m1[tt][r], dlt);
                int   oi1 = __shfl_xor(i1[tt][r], dlt);
                float om2 = __shfl_xor(m2[tt][r], dlt);
                bool ofirst = (om1 < m1[tt][r]) || (om1 == m1[tt][r] && oi1 < i1[tt][r]);
                float l1   = ofirst ? m1[tt][r] : om1;
                float cand = ofirst ? om2 : m2[tt][r];
                m1[tt][r] = ofirst ? om1 : m1[tt][r];
                i1[tt][r] = ofirst ? oi1 : i1[tt][r];
                m2[tt][r] = fminf(cand, l1);
            }
    }

    // record results; flagged rows -> per-wave LDS bitmap word
    if (nn == 0) {
        #pragma unroll
        for (int tt = 0; tt < 2; ++tt)
            #pragma unroll
            for (int r = 0; r < 4; ++r) {
                int rl = tt * 16 + quad * 4 + r;
                bool flg = (m2[tt][r] - m1[tt][r]) < TGAP;
                rowinfo[w][rl] = i1[tt][r] | (flg ? FLAGBIT : 0);
                if (flg) atomicOr(&flagbits[w], 1u << rl);
            }
    }
    __syncthreads();
    if (tid < 4) bitmap[blockIdx.x * 4 + tid] = flagbits[tid];   // block-owned, no pre-zero

    // coalesced output + loss for certain rows
    float lsum = 0.f;
    #pragma unroll
    for (int tt = 0; tt < 2; ++tt) {
        #pragma unroll
        for (int p = 0; p < 4; ++p) {
            int rl = tt * 16 + p * 4 + quad;
            int info = rowinfo[w][rl];
            if (!(info & FLAGBIT)) {
                int j = info & 511;
                int kb = nn * 4;
                float q0 = cb[(kb + 0) * K + j];
                float q1 = cb[(kb + 1) * K + j];
                float q2 = cb[(kb + 2) * K + j];
                float q3 = cb[(kb + 3) * K + j];
                size_t row = (size_t)rowBase + rl;
                float4 xv = *(const float4*)(x + row * D + kb);
                float e0 = q0 - xv.x, e1 = q1 - xv.y, e2 = q2 - xv.z, e3 = q3 - xv.w;
                lsum += e0 * e0 + e1 * e1 + e2 * e2 + e3 * e3;
                *(float4*)(out + row * D + kb) = make_float4(q0, q1, q2, q3);
            }
        }
    }
    #pragma unroll
    for (int off = 32; off > 0; off >>= 1) lsum += __shfl_down(lsum, off);
    if (lane == 0) wavesum[w] = lsum;
    __syncthreads();
    if (tid == 0) {
        double tot = (double)wavesum[0] + (double)wavesum[1]
                   + (double)wavesum[2] + (double)wavesum[3];
        lpart[blockIdx.x] = tot;                 // plain store: no contention
    }
}

// ---------------------------------------------------------------------------
// Rescan: exact numpy-order pipeline for flagged rows. One wave per 64-row
// bitmap span; lane handles 8 columns (j = lane + 64m). One atomic per wave,
// and only for the ~tens of waves that own a flagged row (no contention).
// ---------------------------------------------------------------------------
__global__ __launch_bounds__(256) void vq_rescan(const float* __restrict__ x,
                                                 const float* __restrict__ cb,
                                                 float* __restrict__ out,
                                                 double* __restrict__ loss_acc,
                                                 const unsigned int* __restrict__ bitmap) {
#pragma clang fp contract(off)
    const int lane = threadIdx.x & 63;
    const int gwave = blockIdx.x * 4 + (threadIdx.x >> 6);   // 0..2047

    unsigned int w0 = bitmap[gwave * 2 + 0];
    unsigned int w1 = bitmap[gwave * 2 + 1];
    unsigned long long mask = ((unsigned long long)w1 << 32) | w0;
    float wloss = 0.f;
    if (mask) {
        // numpy-order column norms for my 8 columns (hoisted across rows)
        float bn[8];
        #pragma unroll
        for (int m = 0; m < 8; ++m) bn[m] = 0.f;
        for (int k = 0; k < D; ++k) {
            const float* crow = cb + k * K + lane;
            #pragma unroll
            for (int m = 0; m < 8; ++m) {
                float c = crow[m * 64];
                bn[m] = bn[m] + c * c;
            }
        }
        while (mask) {
            int b = __builtin_ctzll(mask);
            mask &= mask - 1;
            int row = gwave * 64 + b;
            const float* xr = x + (size_t)row * D;
            // A = np.sum(x**2, axis=1): pairwise n=64 emulation
            float A0;
            {
                float rr[8];
                #pragma unroll
                for (int l = 0; l < 8; ++l) rr[l] = xr[l] * xr[l];
                #pragma unroll
                for (int m = 1; m < 8; ++m)
                    #pragma unroll
                    for (int l = 0; l < 8; ++l) {
                        float q = xr[8 * m + l] * xr[8 * m + l];
                        rr[l] = rr[l] + q;
                    }
                A0 = ((rr[0] + rr[1]) + (rr[2] + rr[3])) + ((rr[4] + rr[5]) + (rr[6] + rr[7]));
            }
            float a[8];
            #pragma unroll
            for (int m = 0; m < 8; ++m) a[m] = 0.f;
            for (int k = 0; k < D; ++k) {
                float xk = xr[k];
                const float* crow = cb + k * K + lane;
                #pragma unroll
                for (int m = 0; m < 8; ++m)
                    a[m] = fmaf(xk, crow[m * 64], a[m]);   // sequential-k fma chain
            }
            float db = INFINITY; int jb = 0x7fffffff;
            #pragma unroll
            for (int m = 0; m < 8; ++m) {
                float s = A0 + bn[m];
                float t2 = 2.0f * a[m];
                float d = s - t2;                  // fl(fl(A+B) - fl(2M))
                int j = lane + (m << 6);
                if (d < db) { db = d; jb = j; }
            }
            for (int s = 1; s < 64; s <<= 1) {     // first-index global argmin
                float od = __shfl_xor(db, s);
                int oj = __shfl_xor(jb, s);
                if ((od < db) || (od == db && oj < jb)) { db = od; jb = oj; }
            }
            float q = cb[lane * K + jb];
            out[(size_t)row * D + lane] = q;
            float e = q - xr[lane];
            wloss += e * e;
        }
    }
    #pragma unroll
    for (int off = 32; off > 0; off >>= 1) wloss += __shfl_down(wloss, off);
    if (lane == 0 && wloss != 0.f) atomicAdd(loss_acc, (double)wloss);
}

// ---------------------------------------------------------------------------
// Finalize: tree-sum the 1024 block partials + rescan accumulator.
// ---------------------------------------------------------------------------
__global__ __launch_bounds__(256) void vq_finalize(const double* __restrict__ lpart,
                                                   const double* __restrict__ acc,
                                                   float* __restrict__ out) {
    __shared__ double ws4[4];
    int tid = threadIdx.x;
    double s = lpart[tid] + lpart[tid + 256] + lpart[tid + 512] + lpart[tid + 768];
    #pragma unroll
    for (int off = 32; off > 0; off >>= 1) s += __shfl_down(s, off);
    if ((tid & 63) == 0) ws4[tid >> 6] = s;
    __syncthreads();
    if (tid == 0) {
        double tot = ws4[0] + ws4[1] + ws4[2] + ws4[3] + acc[0];
        // loss = (1 + beta) * mean((q - x)^2), beta = 0.25
        out[NELEM] = (float)(tot * (1.25 / (double)NELEM));
    }
}

extern "C" void kernel_launch(void* const* d_in, const int* in_sizes, int n_in,
                              void* d_out, int out_size, void* d_ws, size_t ws_size,
                              hipStream_t stream) {
    const float* x  = (const float*)d_in[0];   // [32,64,64,64] fp32
    const float* cb = (const float*)d_in[1];   // [64,512] fp32
    float* out = (float*)d_out;                // [8388608] out + [1] loss
    double* loss_acc = (double*)d_ws;
    float* Bn        = (float*)((char*)d_ws + 4096);
    _Float16* gH     = (_Float16*)((char*)d_ws + 8192);
    _Float16* gL     = (_Float16*)((char*)d_ws + 73728);
    unsigned int* bm = (unsigned int*)((char*)d_ws + 139264);
    double* lpart    = (double*)((char*)d_ws + 155648);

    vq_setup<<<64, 512, 0, stream>>>(cb, gH, gL, Bn, (unsigned long long*)d_ws);
    vq_main<<<NBLK, 256, 0, stream>>>(x, cb, gH, gL, Bn, out, lpart, bm);
    vq_rescan<<<512, 256, 0, stream>>>(x, cb, out, loss_acc, bm);
    vq_finalize<<<1, 256, 0, stream>>>(lpart, loss_acc, out);
}